// Round 12
// baseline (256.359 us; speedup 1.0000x reference)
//
#include <hip/hip_runtime.h>
#include <math.h>

typedef float v2f __attribute__((ext_vector_type(2)));

namespace {

constexpr int C_DIM = 4;
constexpr int D_DIM = 64;
constexpr int H_DIM = 160;
constexpr int W_DIM = 160;

constexpr int TH = 20;
constexpr int TW = 20;
constexpr int HALO = 5;
constexpr int EH = 30;
constexpr int EW = 30;
constexpr int XST = 34;          // v2f stride of xy rows; EVEN so every row is
                                 // 16B-aligned (34*8=272) -> b128 reads; quad
                                 // spread (whh+2k)%8 uniform -> no hot banks
constexpr int MST = 21;          // float4 stride of mid rows (odd)
constexpr int NPAIR = EH * EW / 2;  // 450 pixel-pairs per slice

constexpr int TILES_W = 8;       // 160/20
constexpr int TPC = 64;          // 8x8 tiles per (b,c)
constexpr int NBLOCKS = 2 * C_DIM * TPC;  // 512 = exactly 2 blocks/CU

constexpr float C1f = 1e-4f;
constexpr float C2f = 9e-4f;
constexpr float INV_N = 1.0f / (2.0f * 64.0f * 160.0f * 160.0f);

struct GW { float g[11]; };

}  // namespace

__global__ void finalize_kernel(const float* __restrict__ partial,
                                float* __restrict__ out) {
    const int tid = threadIdx.x;
    const int c = tid >> 6;        // one wave per channel
    const int lane = tid & 63;     // lane == tile index (TPC == 64)
    float s = partial[c * TPC + lane] +
              partial[C_DIM * TPC + c * TPC + lane];
#pragma unroll
    for (int off = 32; off > 0; off >>= 1) s += __shfl_down(s, off, 64);
    if (lane == 0 && c < C_DIM) out[c] = 1.0f - s * INV_N;
}

// __launch_bounds__ second arg MUST stay 2 (VGPR budget 256): at 4 the
// pre-RA pressure estimate (~140) exceeds the 128 cap and the allocator
// demotes the D-window arrays to scratch wholesale (R9/R10: 518 MB spill).
__global__ __launch_bounds__(256, 2) void ssim3d_kernel(
    const float* __restrict__ img1, const float* __restrict__ img2,
    float* __restrict__ partial, GW gwp) {

    const int bid = blockIdx.x;
    const int tile = bid % TPC;
    const int c = (bid / TPC) % C_DIM;
    const int b = bid / (TPC * C_DIM);
    const int h0 = (tile / TILES_W) * TH;
    const int w0 = (tile % TILES_W) * TW;

    const long planeHW = (long)H_DIM * W_DIM;
    const long volbase = (long)(b * C_DIM + c) * D_DIM * planeHW;
    const long org = volbase + (long)(h0 - HALO) * W_DIM + (w0 - HALO);
    const float* __restrict__ p1 = img1 + org;
    const float* __restrict__ p2 = img2 + org;

    const bool interior = (h0 >= HALO) && (h0 + TH + HALO <= H_DIM) &&
                          (w0 >= HALO) && (w0 + TW + HALO <= W_DIM);

    // ---- LDS (both stages double-buffered -> 1 barrier per phase) ----
    __shared__ v2f    xy[2][EH][XST];    // interleaved (x,y); b128 row reads
    __shared__ float4 mid[2][EH][MST];   // W-conv (sx,sy | sq,sp), b128
    __shared__ float  rbuf[4];

    const int tid = threadIdx.x;

    // ---- staging decode: thread owns pixel-PAIRS tid and tid+256 ----
    // pair p -> pixels (hh, w2), (hh, w2+1); hh = p/15, w2 = 2*(p%15).
    int hp_[2], wp_[2], offp_[2];
    bool pok_[2], rv_[2], c0v_[2], c1v_[2];
#pragma unroll
    for (int j = 0; j < 2; ++j) {
        const int pr = tid + j * 256;
        pok_[j] = (pr < NPAIR);
        const int hh = pr / 15;
        const int w2 = (pr - hh * 15) * 2;
        hp_[j] = hh; wp_[j] = w2;
        offp_[j] = hh * W_DIM + w2;
        const int gh = h0 - HALO + hh;
        const int gw = w0 - HALO + w2;
        rv_[j]  = ((unsigned)gh < (unsigned)H_DIM);
        c0v_[j] = ((unsigned)gw < (unsigned)W_DIM);
        c1v_[j] = ((unsigned)(gw + 1) < (unsigned)W_DIM);
    }

    // lv[j] = (x0, y0, x1, y1) for the pair -> one b128 LDS write
    auto fetch_slice = [&](int gs, float4 lv[2]) {
        const long sb = (long)gs * planeHW;
        if (interior) {
#pragma unroll
            for (int j = 0; j < 2; ++j) {
                if (pok_[j]) {
                    const long gi = sb + offp_[j];
                    lv[j] = make_float4(p1[gi], p2[gi], p1[gi + 1], p2[gi + 1]);
                }
            }
        } else {
#pragma unroll
            for (int j = 0; j < 2; ++j) {
                lv[j] = make_float4(0.f, 0.f, 0.f, 0.f);
                if (pok_[j] && rv_[j]) {
                    const long gi = sb + offp_[j];
                    if (c0v_[j]) { lv[j].x = p1[gi];     lv[j].y = p2[gi]; }
                    if (c1v_[j]) { lv[j].z = p1[gi + 1]; lv[j].w = p2[gi + 1]; }
                }
            }
        }
    };
    auto commit_slice = [&](int buf, const float4 lv[2]) {
#pragma unroll
        for (int j = 0; j < 2; ++j)
            if (pok_[j])
                *(float4*)&xy[buf][hp_[j]][wp_[j]] = lv[j];
    };

    // ---- wconv: 150 workers (rows fastest), 4 outputs each, 14 taps read
    // as 7 b128 (row 16B-aligned, wg multiple of 4 v2f).
    const bool wactive = (tid < 150);
    const int whh = tid % 30;
    const int wgo = tid / 30;         // output group 0..4 (w = 4*wgo ..)

    auto wconv = [&](int cur) {
        v2f a0 = {0.f,0.f}, a1 = {0.f,0.f}, a2 = {0.f,0.f}, a3 = {0.f,0.f};
        v2f q0 = {0.f,0.f}, q1 = {0.f,0.f}, q2 = {0.f,0.f}, q3 = {0.f,0.f};
        const float4* rowp = (const float4*)&xy[cur][whh][0];
        const int jb = wgo * 2;       // float4 index of tap 0
#define WTAP(t_, xv_)                                                     \
        {                                                                 \
            v2f qp;                                                       \
            qp.x = fmaf((xv_).x, (xv_).x, (xv_).y * (xv_).y);             \
            qp.y = (xv_).x * (xv_).y;                                     \
            if ((t_) <= 10) {                                             \
                const v2f g2 = {gwp.g[(t_)], gwp.g[(t_)]};                \
                a0 = __builtin_elementwise_fma(g2, (xv_), a0);            \
                q0 = __builtin_elementwise_fma(g2, qp, q0);               \
            }                                                             \
            if ((t_) >= 1 && (t_) <= 11) {                                \
                const v2f g2 = {gwp.g[(t_)-1], gwp.g[(t_)-1]};            \
                a1 = __builtin_elementwise_fma(g2, (xv_), a1);            \
                q1 = __builtin_elementwise_fma(g2, qp, q1);               \
            }                                                             \
            if ((t_) >= 2 && (t_) <= 12) {                                \
                const v2f g2 = {gwp.g[(t_)-2], gwp.g[(t_)-2]};            \
                a2 = __builtin_elementwise_fma(g2, (xv_), a2);            \
                q2 = __builtin_elementwise_fma(g2, qp, q2);               \
            }                                                             \
            if ((t_) >= 3) {                                              \
                const v2f g2 = {gwp.g[(t_)-3], gwp.g[(t_)-3]};            \
                a3 = __builtin_elementwise_fma(g2, (xv_), a3);            \
                q3 = __builtin_elementwise_fma(g2, qp, q3);               \
            }                                                             \
        }
#pragma unroll
        for (int j = 0; j < 7; ++j) {
            const float4 f = rowp[jb + j];
            const v2f xlo = {f.x, f.y};
            const v2f xhi = {f.z, f.w};
            WTAP(2 * j, xlo);
            WTAP(2 * j + 1, xhi);
        }
#undef WTAP
        const int wg = wgo * 4;
        mid[cur][whh][wg]     = make_float4(a0.x, a0.y, q0.x, q0.y);
        mid[cur][whh][wg + 1] = make_float4(a1.x, a1.y, q1.x, q1.y);
        mid[cur][whh][wg + 2] = make_float4(a2.x, a2.y, q2.x, q2.y);
        mid[cur][whh][wg + 3] = make_float4(a3.x, a3.y, q3.x, q3.y);
    };

    // ---- hconv workers: 200 threads, 2 H-outputs each (rows hb, hb+1)
    const bool hworker = (tid < 200);
    const int hw = tid % 20;          // w position
    const int hb = (tid / 20) * 2;    // h base: 0,2,..,18

    float accum = 0.0f;
    auto ssim_add = [&](v2f mxy, v2f mqp) {
        const float m1 = mxy.x, m2 = mxy.y;
        const float q = mqp.x, pp = mqp.y;
        const float m1s = m1 * m1;
        const float m2s = m2 * m2;
        const float m12 = m1 * m2;
        const float spp = q - m1s - m2s;
        const float s12 = pp - m12;
        const float num = (2.0f * m12 + C1f) * (2.0f * s12 + C2f);
        const float den = (m1s + m2s + C1f) * (spp + C2f);
        accum = fmaf(num, __builtin_amdgcn_rcpf(den), accum);
    };

    // two D-windows (outputs h=hb, hb+1): 14 slots, insert at 10+u, consume
    // over [u..u+10], shift by 4 per 4 phases. Static indices only.
    v2f w0xy[14], w0qp[14], w1xy[14], w1qp[14];
#pragma unroll
    for (int i = 0; i < 14; ++i) {
        w0xy[i] = (v2f){0.f, 0.f}; w0qp[i] = (v2f){0.f, 0.f};
        w1xy[i] = (v2f){0.f, 0.f}; w1qp[i] = (v2f){0.f, 0.f};
    }

    // prologue: slice 0 -> buf 0
    {
        float4 lv[2];
        fetch_slice(0, lv);
        commit_slice(0, lv);
    }
    __syncthreads();

    for (int sb = 0; sb < D_DIM; sb += 4) {   // sb mult of 4 -> s&1 == u&1
#pragma unroll
        for (int u = 0; u < 4; ++u) {
            const int s = sb + u;
            float4 lv[2];
            const bool have_next = (s + 1 < D_DIM);
            if (have_next) fetch_slice(s + 1, lv);
            if (wactive) wconv(u & 1);
            if (have_next) commit_slice((u + 1) & 1, lv);
            __syncthreads();
            if (hworker) {
                v2f z0x = {0.f,0.f}, z0q = {0.f,0.f};
                v2f z1x = {0.f,0.f}, z1q = {0.f,0.f};
#pragma unroll
                for (int t = 0; t < 12; ++t) {
                    const float4 m = mid[u & 1][hb + t][hw];
                    const v2f ma = {m.x, m.y};
                    const v2f mb = {m.z, m.w};
                    if (t <= 10) {
                        const v2f g2 = {gwp.g[t], gwp.g[t]};
                        z0x = __builtin_elementwise_fma(g2, ma, z0x);
                        z0q = __builtin_elementwise_fma(g2, mb, z0q);
                    }
                    if (t >= 1) {
                        const v2f g2 = {gwp.g[t-1], gwp.g[t-1]};
                        z1x = __builtin_elementwise_fma(g2, ma, z1x);
                        z1q = __builtin_elementwise_fma(g2, mb, z1q);
                    }
                }
                w0xy[10 + u] = z0x; w0qp[10 + u] = z0q;
                w1xy[10 + u] = z1x; w1qp[10 + u] = z1q;
                if (s >= HALO) {   // output d = s-5
                    v2f mx0 = {0.f,0.f}, mq0 = {0.f,0.f};
                    v2f mx1 = {0.f,0.f}, mq1 = {0.f,0.f};
#pragma unroll
                    for (int t = 0; t < 11; ++t) {
                        const v2f g2 = {gwp.g[t], gwp.g[t]};
                        mx0 = __builtin_elementwise_fma(g2, w0xy[u + t], mx0);
                        mq0 = __builtin_elementwise_fma(g2, w0qp[u + t], mq0);
                        mx1 = __builtin_elementwise_fma(g2, w1xy[u + t], mx1);
                        mq1 = __builtin_elementwise_fma(g2, w1qp[u + t], mq1);
                    }
                    ssim_add(mx0, mq0);
                    ssim_add(mx1, mq1);
                }
            }
        }
        if (hworker) {
#pragma unroll
            for (int k = 0; k < 10; ++k) {
                w0xy[k] = w0xy[k + 4]; w0qp[k] = w0qp[k + 4];
                w1xy[k] = w1xy[k + 4]; w1qp[k] = w1qp[k + 4];
            }
        }
    }

    // epilogue: outputs d = 59..63; windows hold slices 54+k at slot k (0..9)
    if (hworker) {
#pragma unroll
        for (int i = 10; i < 14; ++i) {
            w0xy[i] = (v2f){0.f, 0.f}; w0qp[i] = (v2f){0.f, 0.f};
            w1xy[i] = (v2f){0.f, 0.f}; w1qp[i] = (v2f){0.f, 0.f};
        }
#pragma unroll
        for (int u2 = 0; u2 < 5; ++u2) {   // output d = 59 + u2
            v2f mx0 = {0.f,0.f}, mq0 = {0.f,0.f};
            v2f mx1 = {0.f,0.f}, mq1 = {0.f,0.f};
#pragma unroll
            for (int t = 0; t < 11; ++t) {
                if (u2 + t <= 13) {        // static guard; dropped taps zero
                    const v2f g2 = {gwp.g[t], gwp.g[t]};
                    mx0 = __builtin_elementwise_fma(g2, w0xy[u2 + t], mx0);
                    mq0 = __builtin_elementwise_fma(g2, w0qp[u2 + t], mq0);
                    mx1 = __builtin_elementwise_fma(g2, w1xy[u2 + t], mx1);
                    mq1 = __builtin_elementwise_fma(g2, w1qp[u2 + t], mq1);
                }
            }
            ssim_add(mx0, mq0);
            ssim_add(mx1, mq1);
        }
    }

    // ---- block reduction -> one partial per block ----
#pragma unroll
    for (int off = 32; off > 0; off >>= 1) accum += __shfl_down(accum, off, 64);
    const int wave = tid >> 6;
    const int lane = tid & 63;
    if (lane == 0) rbuf[wave] = accum;
    __syncthreads();
    if (tid == 0) partial[bid] = rbuf[0] + rbuf[1] + rbuf[2] + rbuf[3];
}

extern "C" void kernel_launch(void* const* d_in, const int* in_sizes, int n_in,
                              void* d_out, int out_size, void* d_ws, size_t ws_size,
                              hipStream_t stream) {
    const float* img1 = (const float*)d_in[0];
    const float* img2 = (const float*)d_in[1];
    float* out = (float*)d_out;
    float* partial = (float*)d_ws;   // NBLOCKS floats

    GW gw;
    {
        double gd[11];
        double ssum = 0.0;
        for (int i = 0; i < 11; ++i) {
            const double t = (double)(i - 5);
            gd[i] = exp(-(t * t) / 4.5);
            ssum += gd[i];
        }
        for (int i = 0; i < 11; ++i) gw.g[i] = (float)(gd[i] / ssum);
    }

    ssim3d_kernel<<<NBLOCKS, 256, 0, stream>>>(img1, img2, partial, gw);
    finalize_kernel<<<1, 256, 0, stream>>>(partial, out);
}